// Round 10
// baseline (4522.591 us; speedup 1.0000x reference)
//
#include <hip/hip_runtime.h>

#define NB 256
#define NT 256
#define AGT __HIP_MEMORY_SCOPE_AGENT
typedef unsigned long long ull;
typedef _Float16 f16;
typedef __attribute__((ext_vector_type(8))) _Float16 f16x8;
typedef __attribute__((ext_vector_type(4))) float f32x4;
typedef __attribute__((ext_vector_type(4))) unsigned u32x4;

// B=32, S=24, T=48, hidden 512, gate dim 2048.
// 8 teams x 4 batches (team=w>>5, slot=w&31). Slot owns units 16s..16s+15.
// GATE-MAJOR row map grow(r) = (r&3)*512 + slot*16 + (r>>2): per-lane register
// cell math in all waves. All 3 recurrent weight matrices in registers as MFMA
// A-fragments. B tiles in LDS, 1056B row stride (2-way = free).
// R10: CROSS-PHASE PREFETCH - both tiles consumed in phase k are produced in
// phase k-1, so all 4 exchange loads are ISSUED at the tail of phase k-1 and
// stay in flight across the phase boundary. Phase k only drains vmcnt (loads
// already returned) and checks embedded seqs (retry on straggle). Stage-2
// drain uses vmcnt(1) to skip waiting on our own early h0 store. All drain
// asms carry "+v" deps on the in-flight regs (no hoisted seq reads).
// Exchange: R6-proven seq-embedded 8B chunks (4B fp16x2 + 4B seq), sc0 sc1.

#define BSTR 1056   // B-tile row stride in bytes (528 shorts)

struct __align__(16) SMem {
  unsigned short Bt[2][2][4 * 528]; // [pp][0=h0-src,1=h1-src][4 rows x 528]
  float X[2][4][8];                 // x_t, double-buffered by pp
  int sLens[2][4];
  int sLmax[2];
};

__device__ __forceinline__ float sigm(float x) { return 1.0f / (1.0f + expf(-x)); }
__device__ __forceinline__ unsigned short f16b(float x) {
  union { _Float16 h; unsigned short u; } q; q.h = (_Float16)x; return q.u;
}
__device__ __forceinline__ ull pk4(float a, float b, float c, float d) {
  union { _Float16 h; unsigned short u; } q;
  ull r; q.h = (_Float16)a; r = q.u; q.h = (_Float16)b; r |= (ull)q.u << 16;
  q.h = (_Float16)c; r |= (ull)q.u << 32; q.h = (_Float16)d; r |= (ull)q.u << 48;
  return r;
}
__device__ __forceinline__ u32x4 ld1x16(const void* p) {
  u32x4 r;
  asm volatile("global_load_dwordx4 %0, %1, off sc0 sc1\ns_waitcnt vmcnt(0)"
               : "=&v"(r) : "v"(p) : "memory");
  return r;
}
__device__ __forceinline__ void issue2(const void* p0, const void* p1, u32x4& a, u32x4& b) {
  asm volatile("global_load_dwordx4 %0, %2, off sc0 sc1\n"
               "global_load_dwordx4 %1, %3, off sc0 sc1"
               : "=&v"(a), "=&v"(b) : "v"(p0), "v"(p1) : "memory");
}

extern "C" __global__ void __launch_bounds__(NT, 1)
rnn_decoder_kernel(const float* __restrict__ enc, const float* __restrict__ sketch,
                   const int* __restrict__ slen,
                   const float* __restrict__ Wsc_ih, const float* __restrict__ Wsc_hh,
                   const float* __restrict__ bsc,
                   const float* __restrict__ W0ih, const float* __restrict__ W0hh,
                   const float* __restrict__ b0,
                   const float* __restrict__ W1ih, const float* __restrict__ W1hh,
                   const float* __restrict__ b1,
                   const float* __restrict__ Wout, const float* __restrict__ bout,
                   float* __restrict__ out, float* __restrict__ ws)
{
  extern __shared__ char smraw[];
  SMem* sm = (SMem*)smraw;
  const int tid = threadIdx.x;
  const int w = blockIdx.x;
  const int team = w >> 5, slot = w & 31;
  const int lane = tid & 63;
  const int wq = tid >> 6;
  const int l15 = lane & 15;
  const int kq = lane >> 4;
  const int my_b = l15 & 3;
  const int my_u = wq * 4 + kq;

  ull* tb = (ull*)ws + (size_t)team * 6144;
  ull* h0T = tb;
  ull* h1T = tb + 2048;
  ull* sHg = tb + 4096;

  auto grow = [&](int r) { return ((r & 3) << 9) + slot * 16 + (r >> 2); };

  auto ldsB = [&](const unsigned short* Bp, int st) -> f16x8 {
    return *(const f16x8*)((const char*)Bp + my_b * BSTR + st * 64 + kq * 16);
  };
  auto mfma_gv = [&](const float* W, int stride, int coloff, const unsigned short* Bp, f32x4& acc) {
    const float* rp = W + (size_t)grow(wq * 16 + l15) * stride + coloff;
#pragma unroll
    for (int st = 0; st < 16; ++st) {
      const float* q = rp + st * 32 + kq * 8;
      float4 u0 = *(const float4*)q, u1 = *(const float4*)(q + 4);
      f16x8 a;
      a[0] = (f16)u0.x; a[1] = (f16)u0.y; a[2] = (f16)u0.z; a[3] = (f16)u0.w;
      a[4] = (f16)u1.x; a[5] = (f16)u1.y; a[6] = (f16)u1.z; a[7] = (f16)u1.w;
      acc = __builtin_amdgcn_mfma_f32_16x16x32_f16(a, ldsB(Bp, st), acc, 0, 0, 0);
    }
  };
  auto mfma_gs = [&](const float* W, const unsigned short* Bp, f32x4& acc) {
    const float* rp = W + (size_t)grow(wq * 16 + l15) * 517;
#pragma unroll
    for (int st = 0; st < 16; ++st) {
      const float* q = rp + st * 32 + kq * 8;
      f16x8 a;
#pragma unroll
      for (int j = 0; j < 8; ++j) a[j] = (f16)q[j];
      acc = __builtin_amdgcn_mfma_f32_16x16x32_f16(a, ldsB(Bp, st), acc, 0, 0, 0);
    }
  };

  // ---------- seq-embedded staging ----------
  auto putB = [&](unsigned short* Bp, int p, const u32x4& v) {
    int bb2 = p >> 7, up = (2 * p) & 255;
    *(ull*)((char*)Bp + bb2 * BSTR + up * 4) = (ull)v.x | ((ull)v.z << 32);
  };
  // fused issue+wait (scene / t0 phases)
  auto stageT = [&](const ull* s0, unsigned e0, unsigned short* Bp) {
    const char* p0 = (const char*)s0 + tid * 16;
    const char* p1 = (const char*)s0 + (tid + 256) * 16;
    u32x4 a, b;
    asm volatile("global_load_dwordx4 %0, %2, off sc0 sc1\n"
                 "global_load_dwordx4 %1, %3, off sc0 sc1\n"
                 "s_waitcnt vmcnt(0)"
                 : "=&v"(a), "=&v"(b) : "v"(p0), "v"(p1) : "memory");
    int spins = 0;
    while (((a.y ^ e0) | (a.w ^ e0) | (b.y ^ e0) | (b.w ^ e0)) != 0) {
      if (++spins > 20000) break;          // bailout: garbage > hang
      if (spins > 16) __builtin_amdgcn_s_sleep(1);
      if ((a.y ^ e0) | (a.w ^ e0)) a = ld1x16(p0);
      if ((b.y ^ e0) | (b.w ^ e0)) b = ld1x16(p1);
    }
    putB(Bp, tid, a); putB(Bp, tid + 256, b);
  };
  // poll pre-drained in-flight regs, retry stragglers, stage into LDS
  auto pollB = [&](const ull* s0, unsigned e0, u32x4& a, u32x4& b, unsigned short* Bp) {
    const char* p0 = (const char*)s0 + tid * 16;
    const char* p1 = (const char*)s0 + (tid + 256) * 16;
    int spins = 0;
    while (((a.y ^ e0) | (a.w ^ e0) | (b.y ^ e0) | (b.w ^ e0)) != 0) {
      if (++spins > 20000) break;
      if (spins > 16) __builtin_amdgcn_s_sleep(1);
      if ((a.y ^ e0) | (a.w ^ e0)) a = ld1x16(p0);
      if ((b.y ^ e0) | (b.w ^ e0)) b = ld1x16(p1);
    }
    putB(Bp, tid, a); putB(Bp, tid + 256, b);
  };

  // ---------- init: ALL recurrent weights into registers ----------
  f16x8 w0hh[16], w1ih[16], whh[16];
  {
    const float* r0 = W0hh + (size_t)grow(wq * 16 + l15) * 512;
    const float* r1 = W1ih + (size_t)grow(wq * 16 + l15) * 512;
    const float* r2 = W1hh + (size_t)grow(wq * 16 + l15) * 512;
#pragma unroll
    for (int st = 0; st < 16; ++st) {
      const int o = st * 32 + kq * 8;
      float4 u0, u1;
      f16x8 a;
      u0 = *(const float4*)(r0 + o); u1 = *(const float4*)(r0 + o + 4);
      a[0] = (f16)u0.x; a[1] = (f16)u0.y; a[2] = (f16)u0.z; a[3] = (f16)u0.w;
      a[4] = (f16)u1.x; a[5] = (f16)u1.y; a[6] = (f16)u1.z; a[7] = (f16)u1.w;
      w0hh[st] = a;
      u0 = *(const float4*)(r1 + o); u1 = *(const float4*)(r1 + o + 4);
      a[0] = (f16)u0.x; a[1] = (f16)u0.y; a[2] = (f16)u0.z; a[3] = (f16)u0.w;
      a[4] = (f16)u1.x; a[5] = (f16)u1.y; a[6] = (f16)u1.z; a[7] = (f16)u1.w;
      w1ih[st] = a;
      u0 = *(const float4*)(r2 + o); u1 = *(const float4*)(r2 + o + 4);
      a[0] = (f16)u0.x; a[1] = (f16)u0.y; a[2] = (f16)u0.z; a[3] = (f16)u0.w;
      a[4] = (f16)u1.x; a[5] = (f16)u1.y; a[6] = (f16)u1.z; a[7] = (f16)u1.w;
      whh[st] = a;
    }
  }
  float cb0[4], cb1[4], cbsc[4], cwx[4][5];
  {
    int gu = slot * 16 + my_u;
#pragma unroll
    for (int gi = 0; gi < 4; ++gi) {
      int gr = gi * 512 + gu;
      cb0[gi] = b0[gr]; cb1[gi] = b1[gr]; cbsc[gi] = bsc[gr];
#pragma unroll
      for (int j = 0; j < 5; ++j) cwx[gi][j] = W0ih[(size_t)gr * 517 + 512 + j];
    }
  }
  const int b_o = slot / 5, o_o = slot % 5;
  const bool oslot = (slot < 20);
  float wo[8]; float bo_r = 0.f;
  if (oslot && tid < 64) {
    bo_r = bout[o_o];
#pragma unroll
    for (int j = 0; j < 8; ++j) wo[j] = Wout[o_o * 512 + lane * 8 + j];
  }

  // e0reg = Wsc_ih[:, :512] @ enc  -> per-lane f32x4
  f32x4 e0reg = {0.f, 0.f, 0.f, 0.f};
  {
    int b2 = tid >> 6, c8 = tid & 63;
    const float* q = enc + (size_t)(4 * team + b2) * 512 + c8 * 8;
    float4 u0 = *(const float4*)q, u1 = *(const float4*)(q + 4);
    unsigned short* Bp = &sm->Bt[0][0][0];
    *(ull*)((char*)Bp + b2 * BSTR + c8 * 16) = pk4(u0.x, u0.y, u0.z, u0.w);
    *(ull*)((char*)Bp + b2 * BSTR + c8 * 16 + 8) = pk4(u1.x, u1.y, u1.z, u1.w);
    __syncthreads();
    mfma_gv(Wsc_ih, 1024, 0, Bp, e0reg);
  }

  float o_csc = 0.f, o_c0 = 0.f, o_h0 = 0.f, o_c1 = 0.f, o_h1 = 0.f;
  int pp = 0;
  u32x4 fa = {0,0,0,0}, fb = {0,0,0,0}, fc = {0,0,0,0}, fd = {0,0,0,0};

  for (int s = 0; s < 24; ++s) {
    const unsigned base = 51u * (unsigned)s;

    // ================= scene phase =================
    pp ^= 1;
    {
      int lv = (tid < 32) ? slen[tid * 24 + s] : 0;
      if (tid < 64) {
#pragma unroll
        for (int o2 = 1; o2 < 64; o2 <<= 1) lv = max(lv, __shfl_xor(lv, o2, 64));
        if (tid == 0) sm->sLmax[s & 1] = lv;
      }
      if (tid < 4) sm->sLens[s & 1][tid] = slen[(4 * team + tid) * 24 + s];
    }
    {
      unsigned short* Bp0 = &sm->Bt[pp][0][0];
      unsigned short* Bp1 = &sm->Bt[pp][1][0];
      if (s > 0) {
        stageT(h1T, base, Bp0);
        stageT(sHg + ((s - 1) & 1) * 1024, base - 50u, Bp1);
      }
      __syncthreads();
      f32x4 asc = {0.f, 0.f, 0.f, 0.f};
      if (s > 0) {
        mfma_gv(Wsc_ih, 1024, 512, Bp0, asc);   // prev_tok = final h1
        mfma_gv(Wsc_hh, 512, 0, Bp1, asc);      // scene_h(s-1)
      }
      float g[4];
#pragma unroll
      for (int gi = 0; gi < 4; ++gi) g[gi] = e0reg[gi] + cbsc[gi] + asc[gi];
      float c = sigm(g[1]) * o_csc + sigm(g[0]) * tanhf(g[2]);
      float h = sigm(g[3]) * tanhf(c);
      o_csc = c;
      o_c0 = o_h0 = o_c1 = o_h1 = 0.f;
      float hhi = __shfl_down(h, 16, 64);
      if (((kq & 1) == 0) && (l15 < 4)) {
        int chunk = my_b * 256 + slot * 8 + wq * 2 + (kq >> 1);
        unsigned pay = (unsigned)f16b(h) | ((unsigned)f16b(hhi) << 16);
        __hip_atomic_store(&sHg[(s & 1) * 1024 + chunk],
                           (ull)pay | ((ull)(base + 1u) << 32), __ATOMIC_RELAXED, AGT);
      }
    }

    // ================= t0 pre-step: h0(0) =================
    pp ^= 1;
    f32x4 s0reg = {0.f, 0.f, 0.f, 0.f};
    {
      unsigned short* Bp0 = &sm->Bt[pp][0][0];
      if (tid < 4) {
        float xv[5];
        if (s == 0) { xv[0] = 0.f; xv[1] = 0.f; xv[2] = 1.f; xv[3] = 0.f; xv[4] = 0.f; }
        else {
          int bgl = 4 * team + tid;
          int lp = slen[bgl * 24 + (s - 1)];
          int last = min(max(lp - 1, 0), 47);
          const float* q = sketch + ((bgl * 24 + (s - 1)) * 48 + last) * 5;
#pragma unroll
          for (int j = 0; j < 5; ++j) xv[j] = q[j];
        }
#pragma unroll
        for (int j = 0; j < 5; ++j) sm->X[pp][tid][j] = xv[j];
      }
      stageT(sHg + (s & 1) * 1024, base + 1u, Bp0);
      __syncthreads();
      mfma_gs(W0ih, Bp0, s0reg);
      float g[4];
#pragma unroll
      for (int gi = 0; gi < 4; ++gi) {
        float xd = 0.f;
#pragma unroll
        for (int j = 0; j < 5; ++j) xd += cwx[gi][j] * sm->X[pp][my_b][j];
        g[gi] = s0reg[gi] + cb0[gi] + xd;
      }
      float c = sigm(g[1]) * o_c0 + sigm(g[0]) * tanhf(g[2]);
      o_c0 = c; o_h0 = sigm(g[3]) * tanhf(c);
      float hhi = __shfl_down(o_h0, 16, 64);
      if (((kq & 1) == 0) && (l15 < 4)) {
        int chunk = my_b * 256 + slot * 8 + wq * 2 + (kq >> 1);
        unsigned pay = (unsigned)f16b(o_h0) | ((unsigned)f16b(hhi) << 16);
        __hip_atomic_store(&h0T[chunk],
                           (ull)pay | ((ull)(base + 2u) << 32), __ATOMIC_RELAXED, AGT);
      }
      // prefetch issue for k=0 (B0 = h0T parity 0; no B1 at k=0)
      const char* n0 = (const char*)h0T + tid * 16;
      issue2(n0, n0 + 4096, fa, fb);
    }

    // ================= fused iterations (cross-phase prefetch) =================
    for (int k = 0; k <= 48; ++k) {
      const bool doL0 = (k < 48), doPrev = (k > 0);
      const unsigned eSeq = base + 2u + (unsigned)k, sSeq = eSeq + 1u;
      pp ^= 1;
      unsigned short* B0p = &sm->Bt[pp][0][0];
      unsigned short* B1p = &sm->Bt[pp][1][0];
      if (doL0 && tid < 4) {
        const float* q = sketch + (((4 * team + tid) * 24 + s) * 48 + k) * 5;
#pragma unroll
        for (int j = 0; j < 5; ++j) sm->X[pp][tid][j] = q[j];
      }
      // ---- stage 1: drain prefetched B0, poll seq, MFMA, L0 cell, early h0 store
      asm volatile("s_waitcnt vmcnt(0)" : "+v"(fa), "+v"(fb) :: "memory");
      pollB(h0T + (k & 1) * 1024, eSeq, fa, fb, B0p);
      __syncthreads();

      f32x4 a0 = {0.f, 0.f, 0.f, 0.f}, a1 = {0.f, 0.f, 0.f, 0.f};
      const int Lb = sm->sLens[s & 1][my_b];
      if (doL0) {
#pragma unroll
        for (int st = 0; st < 16; ++st)
          a0 = __builtin_amdgcn_mfma_f32_16x16x32_f16(w0hh[st], ldsB(B0p, st), a0, 0, 0, 0);
        if ((k + 1) <= Lb) {
          float g[4];
#pragma unroll
          for (int gi = 0; gi < 4; ++gi) {
            float xd = 0.f;
#pragma unroll
            for (int j = 0; j < 5; ++j) xd += cwx[gi][j] * sm->X[pp][my_b][j];
            g[gi] = a0[gi] + s0reg[gi] + cb0[gi] + xd;
          }
          float c = sigm(g[1]) * o_c0 + sigm(g[0]) * tanhf(g[2]);
          o_c0 = c; o_h0 = sigm(g[3]) * tanhf(c);
        }
        float hhi0 = __shfl_down(o_h0, 16, 64);
        if (((kq & 1) == 0) && (l15 < 4)) {
          int chunk = my_b * 256 + slot * 8 + wq * 2 + (kq >> 1);
          unsigned p0 = (unsigned)f16b(o_h0) | ((unsigned)f16b(hhi0) << 16);
          __hip_atomic_store(&h0T[((k + 1) & 1) * 1024 + chunk],
                             (ull)p0 | ((ull)sSeq << 32), __ATOMIC_RELAXED, AGT);
        }
      }
      // W1ih MFMAs overlap the (already in flight / retired) B1 + h0-store
#pragma unroll
      for (int st = 0; st < 16; ++st)
        a1 = __builtin_amdgcn_mfma_f32_16x16x32_f16(w1ih[st], ldsB(B0p, st), a1, 0, 0, 0);

      // ---- stage 2: drain prefetched B1 (skip own h0 store via vmcnt(1)), MFMA, L1 cell
      if (doPrev) {
        if (doL0) asm volatile("s_waitcnt vmcnt(1)" : "+v"(fc), "+v"(fd) :: "memory");
        else      asm volatile("s_waitcnt vmcnt(0)" : "+v"(fc), "+v"(fd) :: "memory");
        pollB(h1T + ((k - 1) & 1) * 1024, eSeq, fc, fd, B1p);
        __syncthreads();
#pragma unroll
        for (int st = 0; st < 16; ++st)
          a1 = __builtin_amdgcn_mfma_f32_16x16x32_f16(whh[st], ldsB(B1p, st), a1, 0, 0, 0);
      }
      if (k <= Lb) {
        float g[4];
#pragma unroll
        for (int gi = 0; gi < 4; ++gi) g[gi] = a1[gi] + cb1[gi];
        float c = sigm(g[1]) * o_c1 + sigm(g[0]) * tanhf(g[2]);
        o_c1 = c; o_h1 = sigm(g[3]) * tanhf(c);
      }
      float hhi1 = __shfl_down(o_h1, 16, 64);
      if (((kq & 1) == 0) && (l15 < 4)) {
        int chunk = my_b * 256 + slot * 8 + wq * 2 + (kq >> 1);
        unsigned p1 = (unsigned)f16b(o_h1) | ((unsigned)f16b(hhi1) << 16);
        __hip_atomic_store(&h1T[(k & 1) * 1024 + chunk],
                           (ull)p1 | ((ull)sSeq << 32), __ATOMIC_RELAXED, AGT);
      }
      // ---- tail: prefetch-issue next phase's tiles (both produced this phase)
      if (k < 48) {
        const char* n0 = (const char*)(h0T + ((k + 1) & 1) * 1024) + tid * 16;
        const char* n1 = (const char*)(h1T + (k & 1) * 1024) + tid * 16;
        issue2(n0, n0 + 4096, fa, fb);
        issue2(n1, n1 + 4096, fc, fd);
      }

      // out(k-1) from staged h1(k-1) (B1p), off the producer critical path
      if (doPrev && oslot && tid < 64) {
        f16x8 hv = *(const f16x8*)((const char*)B1p + b_o * BSTR + lane * 16);
        float sd = 0.f;
#pragma unroll
        for (int j = 0; j < 8; ++j) sd += (float)hv[j] * wo[j];
#pragma unroll
        for (int o2 = 1; o2 < 64; o2 <<= 1) sd += __shfl_xor(sd, o2, 64);
        if (tid == 0) {
          int tt = k - 1;
          float val = 0.f;
          if (tt < sm->sLmax[s & 1])
            val = (tt > sm->sLens[s & 1][b_o]) ? bo_r : (sd + bo_r);
          out[(((4 * team + b_o) * 24 + s) * 48 + tt) * 5 + o_o] = val;
        }
      }
    }
  }
}

extern "C" void kernel_launch(void* const* d_in, const int* in_sizes, int n_in,
                              void* d_out, int out_size, void* d_ws, size_t ws_size,
                              hipStream_t stream) {
  (void)in_sizes; (void)n_in; (void)out_size; (void)ws_size;
  // Pad LDS to 96KB: forces 1 block/CU so the persistent grid maps 1:1 to CUs.
  int lds_bytes = 98304;
  hipFuncSetAttribute((const void*)rnn_decoder_kernel,
                      hipFuncAttributeMaxDynamicSharedMemorySize, lds_bytes);
  // zero all team exchange regions (seq 0 != any expected seq >= 1)
  hipMemsetAsync(d_ws, 0, 8 * 6144 * 8, stream);
  rnn_decoder_kernel<<<dim3(NB), dim3(NT), lds_bytes, stream>>>(
      (const float*)d_in[0],   // enc_features
      (const float*)d_in[1],   // vector_sketch
      (const int*)d_in[3],     // batch_stroke_len
      (const float*)d_in[4],   // W_sc_ih
      (const float*)d_in[5],   // W_sc_hh
      (const float*)d_in[6],   // b_sc
      (const float*)d_in[7],   // W0_ih
      (const float*)d_in[8],   // W0_hh
      (const float*)d_in[9],   // b0
      (const float*)d_in[10],  // W1_ih
      (const float*)d_in[11],  // W1_hh
      (const float*)d_in[12],  // b1
      (const float*)d_in[13],  // W_out
      (const float*)d_in[14],  // b_out
      (float*)d_out, (float*)d_ws);
}

// Round 11
// 4378.931 us; speedup vs baseline: 1.0328x; 1.0328x over previous
//
#include <hip/hip_runtime.h>

#define NB 256
#define NT 256
#define AGT __HIP_MEMORY_SCOPE_AGENT
typedef unsigned long long ull;
typedef _Float16 f16;
typedef __attribute__((ext_vector_type(8))) _Float16 f16x8;
typedef __attribute__((ext_vector_type(4))) float f32x4;
typedef __attribute__((ext_vector_type(4))) unsigned u32x4;

// B=32, S=24, T=48, hidden 512, gate dim 2048.
// 8 teams x 4 batches (team=w>>5, slot=w&31). Slot owns units 16s..16s+15.
// GATE-MAJOR row map grow(r) = (r&3)*512 + slot*16 + (r>>2): per-lane register
// cell math in all waves. All 3 recurrent weight matrices in registers as MFMA
// A-fragments. B tiles in LDS, 1056B row stride (2-way = free).
// R11: issue BOTH tiles' loads at PHASE START (B0 produced ~1 phase ago ->
// ready; B1 ~0.6 phase ago -> mostly ready), one vmcnt(0) drain, check B0,
// run stage 1 (W0hh MFMA -> L0 cell -> EARLY h0 store -> W1ih MFMA), then
// check the already-in-register B1 (RTT hidden under stage-1 compute).
// R10's mistake (issue at prev-phase tail = before peers stored) corrected.
// Exchange: R6-proven seq-embedded 8B chunks (4B fp16x2 + 4B seq), sc0 sc1.

#define BSTR 1056   // B-tile row stride in bytes (528 shorts)

struct __align__(16) SMem {
  unsigned short Bt[2][2][4 * 528]; // [pp][0=h0-src,1=h1-src][4 rows x 528]
  float X[2][4][8];                 // x_t, double-buffered by pp
  int sLens[2][4];
  int sLmax[2];
};

__device__ __forceinline__ float sigm(float x) { return 1.0f / (1.0f + expf(-x)); }
__device__ __forceinline__ unsigned short f16b(float x) {
  union { _Float16 h; unsigned short u; } q; q.h = (_Float16)x; return q.u;
}
__device__ __forceinline__ ull pk4(float a, float b, float c, float d) {
  union { _Float16 h; unsigned short u; } q;
  ull r; q.h = (_Float16)a; r = q.u; q.h = (_Float16)b; r |= (ull)q.u << 16;
  q.h = (_Float16)c; r |= (ull)q.u << 32; q.h = (_Float16)d; r |= (ull)q.u << 48;
  return r;
}
__device__ __forceinline__ u32x4 ld1x16(const void* p) {
  u32x4 r;
  asm volatile("global_load_dwordx4 %0, %1, off sc0 sc1\ns_waitcnt vmcnt(0)"
               : "=&v"(r) : "v"(p) : "memory");
  return r;
}
__device__ __forceinline__ void issue2(const void* p0, const void* p1, u32x4& a, u32x4& b) {
  asm volatile("global_load_dwordx4 %0, %2, off sc0 sc1\n"
               "global_load_dwordx4 %1, %3, off sc0 sc1"
               : "=&v"(a), "=&v"(b) : "v"(p0), "v"(p1) : "memory");
}
__device__ __forceinline__ void issue4(const void* p0, const void* p1,
                                       const void* p2, const void* p3,
                                       u32x4& a, u32x4& b, u32x4& c, u32x4& d) {
  asm volatile("global_load_dwordx4 %0, %4, off sc0 sc1\n"
               "global_load_dwordx4 %1, %5, off sc0 sc1\n"
               "global_load_dwordx4 %2, %6, off sc0 sc1\n"
               "global_load_dwordx4 %3, %7, off sc0 sc1"
               : "=&v"(a), "=&v"(b), "=&v"(c), "=&v"(d)
               : "v"(p0), "v"(p1), "v"(p2), "v"(p3) : "memory");
}

extern "C" __global__ void __launch_bounds__(NT, 1)
rnn_decoder_kernel(const float* __restrict__ enc, const float* __restrict__ sketch,
                   const int* __restrict__ slen,
                   const float* __restrict__ Wsc_ih, const float* __restrict__ Wsc_hh,
                   const float* __restrict__ bsc,
                   const float* __restrict__ W0ih, const float* __restrict__ W0hh,
                   const float* __restrict__ b0,
                   const float* __restrict__ W1ih, const float* __restrict__ W1hh,
                   const float* __restrict__ b1,
                   const float* __restrict__ Wout, const float* __restrict__ bout,
                   float* __restrict__ out, float* __restrict__ ws)
{
  extern __shared__ char smraw[];
  SMem* sm = (SMem*)smraw;
  const int tid = threadIdx.x;
  const int w = blockIdx.x;
  const int team = w >> 5, slot = w & 31;
  const int lane = tid & 63;
  const int wq = tid >> 6;
  const int l15 = lane & 15;
  const int kq = lane >> 4;
  const int my_b = l15 & 3;
  const int my_u = wq * 4 + kq;

  ull* tb = (ull*)ws + (size_t)team * 6144;
  ull* h0T = tb;
  ull* h1T = tb + 2048;
  ull* sHg = tb + 4096;

  auto grow = [&](int r) { return ((r & 3) << 9) + slot * 16 + (r >> 2); };

  auto ldsB = [&](const unsigned short* Bp, int st) -> f16x8 {
    return *(const f16x8*)((const char*)Bp + my_b * BSTR + st * 64 + kq * 16);
  };
  auto mfma_gv = [&](const float* W, int stride, int coloff, const unsigned short* Bp, f32x4& acc) {
    const float* rp = W + (size_t)grow(wq * 16 + l15) * stride + coloff;
#pragma unroll
    for (int st = 0; st < 16; ++st) {
      const float* q = rp + st * 32 + kq * 8;
      float4 u0 = *(const float4*)q, u1 = *(const float4*)(q + 4);
      f16x8 a;
      a[0] = (f16)u0.x; a[1] = (f16)u0.y; a[2] = (f16)u0.z; a[3] = (f16)u0.w;
      a[4] = (f16)u1.x; a[5] = (f16)u1.y; a[6] = (f16)u1.z; a[7] = (f16)u1.w;
      acc = __builtin_amdgcn_mfma_f32_16x16x32_f16(a, ldsB(Bp, st), acc, 0, 0, 0);
    }
  };
  auto mfma_gs = [&](const float* W, const unsigned short* Bp, f32x4& acc) {
    const float* rp = W + (size_t)grow(wq * 16 + l15) * 517;
#pragma unroll
    for (int st = 0; st < 16; ++st) {
      const float* q = rp + st * 32 + kq * 8;
      f16x8 a;
#pragma unroll
      for (int j = 0; j < 8; ++j) a[j] = (f16)q[j];
      acc = __builtin_amdgcn_mfma_f32_16x16x32_f16(a, ldsB(Bp, st), acc, 0, 0, 0);
    }
  };

  // ---------- seq-embedded staging ----------
  auto putB = [&](unsigned short* Bp, int p, const u32x4& v) {
    int bb2 = p >> 7, up = (2 * p) & 255;
    *(ull*)((char*)Bp + bb2 * BSTR + up * 4) = (ull)v.x | ((ull)v.z << 32);
  };
  // fused issue+wait (scene / t0 phases)
  auto stageT = [&](const ull* s0, unsigned e0, unsigned short* Bp) {
    const char* p0 = (const char*)s0 + tid * 16;
    const char* p1 = (const char*)s0 + (tid + 256) * 16;
    u32x4 a, b;
    asm volatile("global_load_dwordx4 %0, %2, off sc0 sc1\n"
                 "global_load_dwordx4 %1, %3, off sc0 sc1\n"
                 "s_waitcnt vmcnt(0)"
                 : "=&v"(a), "=&v"(b) : "v"(p0), "v"(p1) : "memory");
    int spins = 0;
    while (((a.y ^ e0) | (a.w ^ e0) | (b.y ^ e0) | (b.w ^ e0)) != 0) {
      if (++spins > 20000) break;          // bailout: garbage > hang
      if (spins > 16) __builtin_amdgcn_s_sleep(1);
      if ((a.y ^ e0) | (a.w ^ e0)) a = ld1x16(p0);
      if ((b.y ^ e0) | (b.w ^ e0)) b = ld1x16(p1);
    }
    putB(Bp, tid, a); putB(Bp, tid + 256, b);
  };
  // poll pre-loaded in-register chunks, retry stragglers, stage into LDS
  auto pollB = [&](const ull* s0, unsigned e0, u32x4& a, u32x4& b, unsigned short* Bp) {
    const char* p0 = (const char*)s0 + tid * 16;
    const char* p1 = (const char*)s0 + (tid + 256) * 16;
    int spins = 0;
    while (((a.y ^ e0) | (a.w ^ e0) | (b.y ^ e0) | (b.w ^ e0)) != 0) {
      if (++spins > 20000) break;
      if (spins > 16) __builtin_amdgcn_s_sleep(1);
      if ((a.y ^ e0) | (a.w ^ e0)) a = ld1x16(p0);
      if ((b.y ^ e0) | (b.w ^ e0)) b = ld1x16(p1);
    }
    putB(Bp, tid, a); putB(Bp, tid + 256, b);
  };

  // ---------- init: ALL recurrent weights into registers ----------
  f16x8 w0hh[16], w1ih[16], whh[16];
  {
    const float* r0 = W0hh + (size_t)grow(wq * 16 + l15) * 512;
    const float* r1 = W1ih + (size_t)grow(wq * 16 + l15) * 512;
    const float* r2 = W1hh + (size_t)grow(wq * 16 + l15) * 512;
#pragma unroll
    for (int st = 0; st < 16; ++st) {
      const int o = st * 32 + kq * 8;
      float4 u0, u1;
      f16x8 a;
      u0 = *(const float4*)(r0 + o); u1 = *(const float4*)(r0 + o + 4);
      a[0] = (f16)u0.x; a[1] = (f16)u0.y; a[2] = (f16)u0.z; a[3] = (f16)u0.w;
      a[4] = (f16)u1.x; a[5] = (f16)u1.y; a[6] = (f16)u1.z; a[7] = (f16)u1.w;
      w0hh[st] = a;
      u0 = *(const float4*)(r1 + o); u1 = *(const float4*)(r1 + o + 4);
      a[0] = (f16)u0.x; a[1] = (f16)u0.y; a[2] = (f16)u0.z; a[3] = (f16)u0.w;
      a[4] = (f16)u1.x; a[5] = (f16)u1.y; a[6] = (f16)u1.z; a[7] = (f16)u1.w;
      w1ih[st] = a;
      u0 = *(const float4*)(r2 + o); u1 = *(const float4*)(r2 + o + 4);
      a[0] = (f16)u0.x; a[1] = (f16)u0.y; a[2] = (f16)u0.z; a[3] = (f16)u0.w;
      a[4] = (f16)u1.x; a[5] = (f16)u1.y; a[6] = (f16)u1.z; a[7] = (f16)u1.w;
      whh[st] = a;
    }
  }
  float cb0[4], cb1[4], cbsc[4], cwx[4][5];
  {
    int gu = slot * 16 + my_u;
#pragma unroll
    for (int gi = 0; gi < 4; ++gi) {
      int gr = gi * 512 + gu;
      cb0[gi] = b0[gr]; cb1[gi] = b1[gr]; cbsc[gi] = bsc[gr];
#pragma unroll
      for (int j = 0; j < 5; ++j) cwx[gi][j] = W0ih[(size_t)gr * 517 + 512 + j];
    }
  }
  const int b_o = slot / 5, o_o = slot % 5;
  const bool oslot = (slot < 20);
  float wo[8]; float bo_r = 0.f;
  if (oslot && tid < 64) {
    bo_r = bout[o_o];
#pragma unroll
    for (int j = 0; j < 8; ++j) wo[j] = Wout[o_o * 512 + lane * 8 + j];
  }

  // e0reg = Wsc_ih[:, :512] @ enc  -> per-lane f32x4
  f32x4 e0reg = {0.f, 0.f, 0.f, 0.f};
  {
    int b2 = tid >> 6, c8 = tid & 63;
    const float* q = enc + (size_t)(4 * team + b2) * 512 + c8 * 8;
    float4 u0 = *(const float4*)q, u1 = *(const float4*)(q + 4);
    unsigned short* Bp = &sm->Bt[0][0][0];
    *(ull*)((char*)Bp + b2 * BSTR + c8 * 16) = pk4(u0.x, u0.y, u0.z, u0.w);
    *(ull*)((char*)Bp + b2 * BSTR + c8 * 16 + 8) = pk4(u1.x, u1.y, u1.z, u1.w);
    __syncthreads();
    mfma_gv(Wsc_ih, 1024, 0, Bp, e0reg);
  }

  float o_csc = 0.f, o_c0 = 0.f, o_h0 = 0.f, o_c1 = 0.f, o_h1 = 0.f;
  int pp = 0;
  u32x4 fa = {0,0,0,0}, fb = {0,0,0,0}, fc = {0,0,0,0}, fd = {0,0,0,0};

  for (int s = 0; s < 24; ++s) {
    const unsigned base = 51u * (unsigned)s;

    // ================= scene phase =================
    pp ^= 1;
    {
      int lv = (tid < 32) ? slen[tid * 24 + s] : 0;
      if (tid < 64) {
#pragma unroll
        for (int o2 = 1; o2 < 64; o2 <<= 1) lv = max(lv, __shfl_xor(lv, o2, 64));
        if (tid == 0) sm->sLmax[s & 1] = lv;
      }
      if (tid < 4) sm->sLens[s & 1][tid] = slen[(4 * team + tid) * 24 + s];
    }
    {
      unsigned short* Bp0 = &sm->Bt[pp][0][0];
      unsigned short* Bp1 = &sm->Bt[pp][1][0];
      if (s > 0) {
        stageT(h1T, base, Bp0);
        stageT(sHg + ((s - 1) & 1) * 1024, base - 50u, Bp1);
      }
      __syncthreads();
      f32x4 asc = {0.f, 0.f, 0.f, 0.f};
      if (s > 0) {
        mfma_gv(Wsc_ih, 1024, 512, Bp0, asc);   // prev_tok = final h1
        mfma_gv(Wsc_hh, 512, 0, Bp1, asc);      // scene_h(s-1)
      }
      float g[4];
#pragma unroll
      for (int gi = 0; gi < 4; ++gi) g[gi] = e0reg[gi] + cbsc[gi] + asc[gi];
      float c = sigm(g[1]) * o_csc + sigm(g[0]) * tanhf(g[2]);
      float h = sigm(g[3]) * tanhf(c);
      o_csc = c;
      o_c0 = o_h0 = o_c1 = o_h1 = 0.f;
      float hhi = __shfl_down(h, 16, 64);
      if (((kq & 1) == 0) && (l15 < 4)) {
        int chunk = my_b * 256 + slot * 8 + wq * 2 + (kq >> 1);
        unsigned pay = (unsigned)f16b(h) | ((unsigned)f16b(hhi) << 16);
        __hip_atomic_store(&sHg[(s & 1) * 1024 + chunk],
                           (ull)pay | ((ull)(base + 1u) << 32), __ATOMIC_RELAXED, AGT);
      }
    }

    // ================= t0 pre-step: h0(0) =================
    pp ^= 1;
    f32x4 s0reg = {0.f, 0.f, 0.f, 0.f};
    {
      unsigned short* Bp0 = &sm->Bt[pp][0][0];
      if (tid < 4) {
        float xv[5];
        if (s == 0) { xv[0] = 0.f; xv[1] = 0.f; xv[2] = 1.f; xv[3] = 0.f; xv[4] = 0.f; }
        else {
          int bgl = 4 * team + tid;
          int lp = slen[bgl * 24 + (s - 1)];
          int last = min(max(lp - 1, 0), 47);
          const float* q = sketch + ((bgl * 24 + (s - 1)) * 48 + last) * 5;
#pragma unroll
          for (int j = 0; j < 5; ++j) xv[j] = q[j];
        }
#pragma unroll
        for (int j = 0; j < 5; ++j) sm->X[pp][tid][j] = xv[j];
      }
      stageT(sHg + (s & 1) * 1024, base + 1u, Bp0);
      __syncthreads();
      mfma_gs(W0ih, Bp0, s0reg);
      float g[4];
#pragma unroll
      for (int gi = 0; gi < 4; ++gi) {
        float xd = 0.f;
#pragma unroll
        for (int j = 0; j < 5; ++j) xd += cwx[gi][j] * sm->X[pp][my_b][j];
        g[gi] = s0reg[gi] + cb0[gi] + xd;
      }
      float c = sigm(g[1]) * o_c0 + sigm(g[0]) * tanhf(g[2]);
      o_c0 = c; o_h0 = sigm(g[3]) * tanhf(c);
      float hhi = __shfl_down(o_h0, 16, 64);
      if (((kq & 1) == 0) && (l15 < 4)) {
        int chunk = my_b * 256 + slot * 8 + wq * 2 + (kq >> 1);
        unsigned pay = (unsigned)f16b(o_h0) | ((unsigned)f16b(hhi) << 16);
        __hip_atomic_store(&h0T[chunk],
                           (ull)pay | ((ull)(base + 2u) << 32), __ATOMIC_RELAXED, AGT);
      }
    }

    // ================= fused iterations =================
    for (int k = 0; k <= 48; ++k) {
      const bool doL0 = (k < 48), doPrev = (k > 0);
      const unsigned eSeq = base + 2u + (unsigned)k, sSeq = eSeq + 1u;
      pp ^= 1;
      unsigned short* B0p = &sm->Bt[pp][0][0];
      unsigned short* B1p = &sm->Bt[pp][1][0];

      // ---- phase start: issue BOTH tiles' loads ----
      {
        const char* n0 = (const char*)(h0T + (k & 1) * 1024) + tid * 16;
        if (doPrev) {
          const char* n1 = (const char*)(h1T + ((k - 1) & 1) * 1024) + tid * 16;
          issue4(n0, n0 + 4096, n1, n1 + 4096, fa, fb, fc, fd);
        } else {
          issue2(n0, n0 + 4096, fa, fb);
        }
      }
      if (doL0 && tid < 4) {
        const float* q = sketch + (((4 * team + tid) * 24 + s) * 48 + k) * 5;
#pragma unroll
        for (int j = 0; j < 5; ++j) sm->X[pp][tid][j] = q[j];
      }
      // drain everything (loads + lingering stores), then check B0
      asm volatile("s_waitcnt vmcnt(0)"
                   : "+v"(fa), "+v"(fb), "+v"(fc), "+v"(fd) :: "memory");
      pollB(h0T + (k & 1) * 1024, eSeq, fa, fb, B0p);
      __syncthreads();

      // ---- stage 1: W0hh MFMA, L0 cell, EARLY h0 store, W1ih MFMA ----
      f32x4 a0 = {0.f, 0.f, 0.f, 0.f}, a1 = {0.f, 0.f, 0.f, 0.f};
      const int Lb = sm->sLens[s & 1][my_b];
      if (doL0) {
#pragma unroll
        for (int st = 0; st < 16; ++st)
          a0 = __builtin_amdgcn_mfma_f32_16x16x32_f16(w0hh[st], ldsB(B0p, st), a0, 0, 0, 0);
        if ((k + 1) <= Lb) {
          float g[4];
#pragma unroll
          for (int gi = 0; gi < 4; ++gi) {
            float xd = 0.f;
#pragma unroll
            for (int j = 0; j < 5; ++j) xd += cwx[gi][j] * sm->X[pp][my_b][j];
            g[gi] = a0[gi] + s0reg[gi] + cb0[gi] + xd;
          }
          float c = sigm(g[1]) * o_c0 + sigm(g[0]) * tanhf(g[2]);
          o_c0 = c; o_h0 = sigm(g[3]) * tanhf(c);
        }
        float hhi0 = __shfl_down(o_h0, 16, 64);
        if (((kq & 1) == 0) && (l15 < 4)) {
          int chunk = my_b * 256 + slot * 8 + wq * 2 + (kq >> 1);
          unsigned p0 = (unsigned)f16b(o_h0) | ((unsigned)f16b(hhi0) << 16);
          __hip_atomic_store(&h0T[((k + 1) & 1) * 1024 + chunk],
                             (ull)p0 | ((ull)sSeq << 32), __ATOMIC_RELAXED, AGT);
        }
      }
#pragma unroll
      for (int st = 0; st < 16; ++st)
        a1 = __builtin_amdgcn_mfma_f32_16x16x32_f16(w1ih[st], ldsB(B0p, st), a1, 0, 0, 0);

      // ---- stage 2: B1 already in registers (RTT hidden under stage 1) ----
      if (doPrev) {
        pollB(h1T + ((k - 1) & 1) * 1024, eSeq, fc, fd, B1p);
        __syncthreads();
#pragma unroll
        for (int st = 0; st < 16; ++st)
          a1 = __builtin_amdgcn_mfma_f32_16x16x32_f16(whh[st], ldsB(B1p, st), a1, 0, 0, 0);
      }
      if (k <= Lb) {
        float g[4];
#pragma unroll
        for (int gi = 0; gi < 4; ++gi) g[gi] = a1[gi] + cb1[gi];
        float c = sigm(g[1]) * o_c1 + sigm(g[0]) * tanhf(g[2]);
        o_c1 = c; o_h1 = sigm(g[3]) * tanhf(c);
      }
      float hhi1 = __shfl_down(o_h1, 16, 64);
      if (((kq & 1) == 0) && (l15 < 4)) {
        int chunk = my_b * 256 + slot * 8 + wq * 2 + (kq >> 1);
        unsigned p1 = (unsigned)f16b(o_h1) | ((unsigned)f16b(hhi1) << 16);
        __hip_atomic_store(&h1T[(k & 1) * 1024 + chunk],
                           (ull)p1 | ((ull)sSeq << 32), __ATOMIC_RELAXED, AGT);
      }

      // out(k-1) from staged h1(k-1) (B1p), off the producer critical path
      if (doPrev && oslot && tid < 64) {
        f16x8 hv = *(const f16x8*)((const char*)B1p + b_o * BSTR + lane * 16);
        float sd = 0.f;
#pragma unroll
        for (int j = 0; j < 8; ++j) sd += (float)hv[j] * wo[j];
#pragma unroll
        for (int o2 = 1; o2 < 64; o2 <<= 1) sd += __shfl_xor(sd, o2, 64);
        if (tid == 0) {
          int tt = k - 1;
          float val = 0.f;
          if (tt < sm->sLmax[s & 1])
            val = (tt > sm->sLens[s & 1][b_o]) ? bo_r : (sd + bo_r);
          out[(((4 * team + b_o) * 24 + s) * 48 + tt) * 5 + o_o] = val;
        }
      }
    }
  }
}

extern "C" void kernel_launch(void* const* d_in, const int* in_sizes, int n_in,
                              void* d_out, int out_size, void* d_ws, size_t ws_size,
                              hipStream_t stream) {
  (void)in_sizes; (void)n_in; (void)out_size; (void)ws_size;
  // Pad LDS to 96KB: forces 1 block/CU so the persistent grid maps 1:1 to CUs.
  int lds_bytes = 98304;
  hipFuncSetAttribute((const void*)rnn_decoder_kernel,
                      hipFuncAttributeMaxDynamicSharedMemorySize, lds_bytes);
  // zero all team exchange regions (seq 0 != any expected seq >= 1)
  hipMemsetAsync(d_ws, 0, 8 * 6144 * 8, stream);
  rnn_decoder_kernel<<<dim3(NB), dim3(NT), lds_bytes, stream>>>(
      (const float*)d_in[0],   // enc_features
      (const float*)d_in[1],   // vector_sketch
      (const int*)d_in[3],     // batch_stroke_len
      (const float*)d_in[4],   // W_sc_ih
      (const float*)d_in[5],   // W_sc_hh
      (const float*)d_in[6],   // b_sc
      (const float*)d_in[7],   // W0_ih
      (const float*)d_in[8],   // W0_hh
      (const float*)d_in[9],   // b0
      (const float*)d_in[10],  // W1_ih
      (const float*)d_in[11],  // W1_hh
      (const float*)d_in[12],  // b1
      (const float*)d_in[13],  // W_out
      (const float*)d_in[14],  // b_out
      (float*)d_out, (float*)d_ws);
}

// Round 12
// 4057.215 us; speedup vs baseline: 1.1147x; 1.0793x over previous
//
#include <hip/hip_runtime.h>

#define NB 256
#define NT 256
#define AGT __HIP_MEMORY_SCOPE_AGENT
typedef unsigned long long ull;
typedef _Float16 f16;
typedef __attribute__((ext_vector_type(8))) _Float16 f16x8;
typedef __attribute__((ext_vector_type(4))) float f32x4;

// B=32, S=24, T=48, hidden 512, gate dim 2048.
// 8 teams x 4 batches (team=w>>5, slot=w&31). Slot owns units 16s..16s+15.
// GATE-MAJOR row map grow(r) = (r&3)*512 + slot*16 + (r>>2): per-lane register
// cell math in all waves. All 3 recurrent weight matrices in registers as MFMA
// A-fragments. B tiles in LDS, 1056B row stride (2-way = free).
// R12 = R9 split-wait skeleton with ONE change: ALL exchange loads are
// compiler-emitted agent-scope relaxed atomics (__hip_atomic_load), the
// R3/R4-proven encoding that is served at the LLC. R6-R11's hand-written
// "sc0 sc1" was SYSTEM scope -> serviced memory-side (FETCH_SIZE ~1GB/dispatch,
// 253 GB/s of pointless HBM traffic, ~2x the observe latency).
// Exchange chunks: 8B = 4B fp16x2 payload + 4B seq; per-chunk retry.

#define BSTR 1056   // B-tile row stride in bytes (528 shorts)

struct __align__(16) SMem {
  unsigned short Bt[2][2][4 * 528]; // [pp][0=h0-src,1=h1-src][4 rows x 528]
  float X[2][4][8];                 // x_t, double-buffered by pp
  int sLens[2][4];
  int sLmax[2];
};

__device__ __forceinline__ float sigm(float x) { return 1.0f / (1.0f + expf(-x)); }
__device__ __forceinline__ unsigned short f16b(float x) {
  union { _Float16 h; unsigned short u; } q; q.h = (_Float16)x; return q.u;
}
__device__ __forceinline__ ull pk4(float a, float b, float c, float d) {
  union { _Float16 h; unsigned short u; } q;
  ull r; q.h = (_Float16)a; r = q.u; q.h = (_Float16)b; r |= (ull)q.u << 16;
  q.h = (_Float16)c; r |= (ull)q.u << 32; q.h = (_Float16)d; r |= (ull)q.u << 48;
  return r;
}
__device__ __forceinline__ ull lda8(const ull* p) {
  return __hip_atomic_load(p, __ATOMIC_RELAXED, AGT);
}

extern "C" __global__ void __launch_bounds__(NT, 1)
rnn_decoder_kernel(const float* __restrict__ enc, const float* __restrict__ sketch,
                   const int* __restrict__ slen,
                   const float* __restrict__ Wsc_ih, const float* __restrict__ Wsc_hh,
                   const float* __restrict__ bsc,
                   const float* __restrict__ W0ih, const float* __restrict__ W0hh,
                   const float* __restrict__ b0,
                   const float* __restrict__ W1ih, const float* __restrict__ W1hh,
                   const float* __restrict__ b1,
                   const float* __restrict__ Wout, const float* __restrict__ bout,
                   float* __restrict__ out, float* __restrict__ ws)
{
  extern __shared__ char smraw[];
  SMem* sm = (SMem*)smraw;
  const int tid = threadIdx.x;
  const int w = blockIdx.x;
  const int team = w >> 5, slot = w & 31;
  const int lane = tid & 63;
  const int wq = tid >> 6;
  const int l15 = lane & 15;
  const int kq = lane >> 4;
  const int my_b = l15 & 3;
  const int my_u = wq * 4 + kq;

  ull* tb = (ull*)ws + (size_t)team * 6144;
  ull* h0T = tb;
  ull* h1T = tb + 2048;
  ull* sHg = tb + 4096;

  auto grow = [&](int r) { return ((r & 3) << 9) + slot * 16 + (r >> 2); };

  auto ldsB = [&](const unsigned short* Bp, int st) -> f16x8 {
    return *(const f16x8*)((const char*)Bp + my_b * BSTR + st * 64 + kq * 16);
  };
  auto mfma_gv = [&](const float* W, int stride, int coloff, const unsigned short* Bp, f32x4& acc) {
    const float* rp = W + (size_t)grow(wq * 16 + l15) * stride + coloff;
#pragma unroll
    for (int st = 0; st < 16; ++st) {
      const float* q = rp + st * 32 + kq * 8;
      float4 u0 = *(const float4*)q, u1 = *(const float4*)(q + 4);
      f16x8 a;
      a[0] = (f16)u0.x; a[1] = (f16)u0.y; a[2] = (f16)u0.z; a[3] = (f16)u0.w;
      a[4] = (f16)u1.x; a[5] = (f16)u1.y; a[6] = (f16)u1.z; a[7] = (f16)u1.w;
      acc = __builtin_amdgcn_mfma_f32_16x16x32_f16(a, ldsB(Bp, st), acc, 0, 0, 0);
    }
  };
  auto mfma_gs = [&](const float* W, const unsigned short* Bp, f32x4& acc) {
    const float* rp = W + (size_t)grow(wq * 16 + l15) * 517;
#pragma unroll
    for (int st = 0; st < 16; ++st) {
      const float* q = rp + st * 32 + kq * 8;
      f16x8 a;
#pragma unroll
      for (int j = 0; j < 8; ++j) a[j] = (f16)q[j];
      acc = __builtin_amdgcn_mfma_f32_16x16x32_f16(a, ldsB(Bp, st), acc, 0, 0, 0);
    }
  };

  // ---------- seq-embedded staging (agent-scope compiler atomics) ----------
  // tile chunk layout: chunk i: batch=i>>8, unit-pair=i&255 (8B = pay|seq).
  // thread tid handles chunk pairs (2tid,2tid+1) and (512+2tid, 513+2tid).
  auto stage4 = [&](const ull* s0, unsigned e0, unsigned short* Bp) {
    const ull* pA = s0 + 2 * tid;
    const ull* pB = pA + 1;
    const ull* pC = s0 + 512 + 2 * tid;
    const ull* pD = pC + 1;
    ull a = lda8(pA), b = lda8(pB), c = lda8(pC), d = lda8(pD);
    int spins = 0;
    while ((((unsigned)(a >> 32) ^ e0) | ((unsigned)(b >> 32) ^ e0) |
            ((unsigned)(c >> 32) ^ e0) | ((unsigned)(d >> 32) ^ e0)) != 0) {
      if (++spins > 40000) break;          // bailout: garbage > hang
      if (spins > 16) __builtin_amdgcn_s_sleep(1);
      if ((unsigned)(a >> 32) != e0) a = lda8(pA);
      if ((unsigned)(b >> 32) != e0) b = lda8(pB);
      if ((unsigned)(c >> 32) != e0) c = lda8(pC);
      if ((unsigned)(d >> 32) != e0) d = lda8(pD);
    }
    {
      int bb2 = tid >> 7, up = (2 * tid) & 255;
      *(ull*)((char*)Bp + bb2 * BSTR + up * 4) =
          (ull)(unsigned)a | ((ull)(unsigned)b << 32);
      int t2 = tid + 256;
      int bb3 = t2 >> 7, up2 = (2 * t2) & 255;
      *(ull*)((char*)Bp + bb3 * BSTR + up2 * 4) =
          (ull)(unsigned)c | ((ull)(unsigned)d << 32);
    }
  };

  // ---------- init: ALL recurrent weights into registers ----------
  f16x8 w0hh[16], w1ih[16], whh[16];
  {
    const float* r0 = W0hh + (size_t)grow(wq * 16 + l15) * 512;
    const float* r1 = W1ih + (size_t)grow(wq * 16 + l15) * 512;
    const float* r2 = W1hh + (size_t)grow(wq * 16 + l15) * 512;
#pragma unroll
    for (int st = 0; st < 16; ++st) {
      const int o = st * 32 + kq * 8;
      float4 u0, u1;
      f16x8 a;
      u0 = *(const float4*)(r0 + o); u1 = *(const float4*)(r0 + o + 4);
      a[0] = (f16)u0.x; a[1] = (f16)u0.y; a[2] = (f16)u0.z; a[3] = (f16)u0.w;
      a[4] = (f16)u1.x; a[5] = (f16)u1.y; a[6] = (f16)u1.z; a[7] = (f16)u1.w;
      w0hh[st] = a;
      u0 = *(const float4*)(r1 + o); u1 = *(const float4*)(r1 + o + 4);
      a[0] = (f16)u0.x; a[1] = (f16)u0.y; a[2] = (f16)u0.z; a[3] = (f16)u0.w;
      a[4] = (f16)u1.x; a[5] = (f16)u1.y; a[6] = (f16)u1.z; a[7] = (f16)u1.w;
      w1ih[st] = a;
      u0 = *(const float4*)(r2 + o); u1 = *(const float4*)(r2 + o + 4);
      a[0] = (f16)u0.x; a[1] = (f16)u0.y; a[2] = (f16)u0.z; a[3] = (f16)u0.w;
      a[4] = (f16)u1.x; a[5] = (f16)u1.y; a[6] = (f16)u1.z; a[7] = (f16)u1.w;
      whh[st] = a;
    }
  }
  float cb0[4], cb1[4], cbsc[4], cwx[4][5];
  {
    int gu = slot * 16 + my_u;
#pragma unroll
    for (int gi = 0; gi < 4; ++gi) {
      int gr = gi * 512 + gu;
      cb0[gi] = b0[gr]; cb1[gi] = b1[gr]; cbsc[gi] = bsc[gr];
#pragma unroll
      for (int j = 0; j < 5; ++j) cwx[gi][j] = W0ih[(size_t)gr * 517 + 512 + j];
    }
  }
  const int b_o = slot / 5, o_o = slot % 5;
  const bool oslot = (slot < 20);
  float wo[8]; float bo_r = 0.f;
  if (oslot && tid < 64) {
    bo_r = bout[o_o];
#pragma unroll
    for (int j = 0; j < 8; ++j) wo[j] = Wout[o_o * 512 + lane * 8 + j];
  }

  // e0reg = Wsc_ih[:, :512] @ enc  -> per-lane f32x4
  f32x4 e0reg = {0.f, 0.f, 0.f, 0.f};
  {
    int b2 = tid >> 6, c8 = tid & 63;
    const float* q = enc + (size_t)(4 * team + b2) * 512 + c8 * 8;
    float4 u0 = *(const float4*)q, u1 = *(const float4*)(q + 4);
    unsigned short* Bp = &sm->Bt[0][0][0];
    *(ull*)((char*)Bp + b2 * BSTR + c8 * 16) = pk4(u0.x, u0.y, u0.z, u0.w);
    *(ull*)((char*)Bp + b2 * BSTR + c8 * 16 + 8) = pk4(u1.x, u1.y, u1.z, u1.w);
    __syncthreads();
    mfma_gv(Wsc_ih, 1024, 0, Bp, e0reg);
  }

  float o_csc = 0.f, o_c0 = 0.f, o_h0 = 0.f, o_c1 = 0.f, o_h1 = 0.f;
  int pp = 0;

  for (int s = 0; s < 24; ++s) {
    const unsigned base = 51u * (unsigned)s;

    // ================= scene phase =================
    pp ^= 1;
    {
      int lv = (tid < 32) ? slen[tid * 24 + s] : 0;
      if (tid < 64) {
#pragma unroll
        for (int o2 = 1; o2 < 64; o2 <<= 1) lv = max(lv, __shfl_xor(lv, o2, 64));
        if (tid == 0) sm->sLmax[s & 1] = lv;
      }
      if (tid < 4) sm->sLens[s & 1][tid] = slen[(4 * team + tid) * 24 + s];
    }
    {
      unsigned short* Bp0 = &sm->Bt[pp][0][0];
      unsigned short* Bp1 = &sm->Bt[pp][1][0];
      if (s > 0) {
        stage4(h1T, base, Bp0);
        stage4(sHg + ((s - 1) & 1) * 1024, base - 50u, Bp1);
      }
      __syncthreads();
      f32x4 asc = {0.f, 0.f, 0.f, 0.f};
      if (s > 0) {
        mfma_gv(Wsc_ih, 1024, 512, Bp0, asc);   // prev_tok = final h1
        mfma_gv(Wsc_hh, 512, 0, Bp1, asc);      // scene_h(s-1)
      }
      float g[4];
#pragma unroll
      for (int gi = 0; gi < 4; ++gi) g[gi] = e0reg[gi] + cbsc[gi] + asc[gi];
      float c = sigm(g[1]) * o_csc + sigm(g[0]) * tanhf(g[2]);
      float h = sigm(g[3]) * tanhf(c);
      o_csc = c;
      o_c0 = o_h0 = o_c1 = o_h1 = 0.f;
      float hhi = __shfl_down(h, 16, 64);
      if (((kq & 1) == 0) && (l15 < 4)) {
        int chunk = my_b * 256 + slot * 8 + wq * 2 + (kq >> 1);
        unsigned pay = (unsigned)f16b(h) | ((unsigned)f16b(hhi) << 16);
        __hip_atomic_store(&sHg[(s & 1) * 1024 + chunk],
                           (ull)pay | ((ull)(base + 1u) << 32), __ATOMIC_RELAXED, AGT);
      }
    }

    // ================= t0 pre-step: h0(0) =================
    pp ^= 1;
    f32x4 s0reg = {0.f, 0.f, 0.f, 0.f};
    {
      unsigned short* Bp0 = &sm->Bt[pp][0][0];
      if (tid < 4) {
        float xv[5];
        if (s == 0) { xv[0] = 0.f; xv[1] = 0.f; xv[2] = 1.f; xv[3] = 0.f; xv[4] = 0.f; }
        else {
          int bgl = 4 * team + tid;
          int lp = slen[bgl * 24 + (s - 1)];
          int last = min(max(lp - 1, 0), 47);
          const float* q = sketch + ((bgl * 24 + (s - 1)) * 48 + last) * 5;
#pragma unroll
          for (int j = 0; j < 5; ++j) xv[j] = q[j];
        }
#pragma unroll
        for (int j = 0; j < 5; ++j) sm->X[pp][tid][j] = xv[j];
      }
      stage4(sHg + (s & 1) * 1024, base + 1u, Bp0);
      __syncthreads();
      mfma_gs(W0ih, Bp0, s0reg);
      float g[4];
#pragma unroll
      for (int gi = 0; gi < 4; ++gi) {
        float xd = 0.f;
#pragma unroll
        for (int j = 0; j < 5; ++j) xd += cwx[gi][j] * sm->X[pp][my_b][j];
        g[gi] = s0reg[gi] + cb0[gi] + xd;
      }
      float c = sigm(g[1]) * o_c0 + sigm(g[0]) * tanhf(g[2]);
      o_c0 = c; o_h0 = sigm(g[3]) * tanhf(c);
      float hhi = __shfl_down(o_h0, 16, 64);
      if (((kq & 1) == 0) && (l15 < 4)) {
        int chunk = my_b * 256 + slot * 8 + wq * 2 + (kq >> 1);
        unsigned pay = (unsigned)f16b(o_h0) | ((unsigned)f16b(hhi) << 16);
        __hip_atomic_store(&h0T[chunk],
                           (ull)pay | ((ull)(base + 2u) << 32), __ATOMIC_RELAXED, AGT);
      }
    }

    // ================= fused iterations (split-wait pipeline) =================
    for (int k = 0; k <= 48; ++k) {
      const bool doL0 = (k < 48), doPrev = (k > 0);
      const unsigned eSeq = base + 2u + (unsigned)k, sSeq = eSeq + 1u;
      pp ^= 1;
      unsigned short* B0p = &sm->Bt[pp][0][0];
      unsigned short* B1p = &sm->Bt[pp][1][0];
      if (doL0 && tid < 4) {
        const float* q = sketch + (((4 * team + tid) * 24 + s) * 48 + k) * 5;
#pragma unroll
        for (int j = 0; j < 5; ++j) sm->X[pp][tid][j] = q[j];
      }
      // ---- stage 1: h0 tile, B0-dependent MFMAs, L0 cell, EARLY h0 store ----
      stage4(h0T + (k & 1) * 1024, eSeq, B0p);
      __syncthreads();

      f32x4 a0 = {0.f, 0.f, 0.f, 0.f}, a1 = {0.f, 0.f, 0.f, 0.f};
#pragma unroll
      for (int st = 0; st < 16; ++st) {
        f16x8 bb = ldsB(B0p, st);
        if (doL0) a0 = __builtin_amdgcn_mfma_f32_16x16x32_f16(w0hh[st], bb, a0, 0, 0, 0);
        a1 = __builtin_amdgcn_mfma_f32_16x16x32_f16(w1ih[st], bb, a1, 0, 0, 0);
      }
      const int Lb = sm->sLens[s & 1][my_b];
      if (doL0) {
        if ((k + 1) <= Lb) {
          float g[4];
#pragma unroll
          for (int gi = 0; gi < 4; ++gi) {
            float xd = 0.f;
#pragma unroll
            for (int j = 0; j < 5; ++j) xd += cwx[gi][j] * sm->X[pp][my_b][j];
            g[gi] = a0[gi] + s0reg[gi] + cb0[gi] + xd;
          }
          float c = sigm(g[1]) * o_c0 + sigm(g[0]) * tanhf(g[2]);
          o_c0 = c; o_h0 = sigm(g[3]) * tanhf(c);
        }
        float hhi0 = __shfl_down(o_h0, 16, 64);
        if (((kq & 1) == 0) && (l15 < 4)) {
          int chunk = my_b * 256 + slot * 8 + wq * 2 + (kq >> 1);
          unsigned p0 = (unsigned)f16b(o_h0) | ((unsigned)f16b(hhi0) << 16);
          __hip_atomic_store(&h0T[((k + 1) & 1) * 1024 + chunk],
                             (ull)p0 | ((ull)sSeq << 32), __ATOMIC_RELAXED, AGT);
        }
      }
      // ---- stage 2: h1 tile, remaining MFMAs, L1 cell, h1 store ----
      if (doPrev) {
        stage4(h1T + ((k - 1) & 1) * 1024, eSeq, B1p);
        __syncthreads();
#pragma unroll
        for (int st = 0; st < 16; ++st)
          a1 = __builtin_amdgcn_mfma_f32_16x16x32_f16(whh[st], ldsB(B1p, st), a1, 0, 0, 0);
      }
      if (k <= Lb) {
        float g[4];
#pragma unroll
        for (int gi = 0; gi < 4; ++gi) g[gi] = a1[gi] + cb1[gi];
        float c = sigm(g[1]) * o_c1 + sigm(g[0]) * tanhf(g[2]);
        o_c1 = c; o_h1 = sigm(g[3]) * tanhf(c);
      }
      float hhi1 = __shfl_down(o_h1, 16, 64);
      if (((kq & 1) == 0) && (l15 < 4)) {
        int chunk = my_b * 256 + slot * 8 + wq * 2 + (kq >> 1);
        unsigned p1 = (unsigned)f16b(o_h1) | ((unsigned)f16b(hhi1) << 16);
        __hip_atomic_store(&h1T[(k & 1) * 1024 + chunk],
                           (ull)p1 | ((ull)sSeq << 32), __ATOMIC_RELAXED, AGT);
      }

      // out(k-1) from staged h1(k-1) (B1p), off the producer critical path
      if (doPrev && oslot && tid < 64) {
        f16x8 hv = *(const f16x8*)((const char*)B1p + b_o * BSTR + lane * 16);
        float sd = 0.f;
#pragma unroll
        for (int j = 0; j < 8; ++j) sd += (float)hv[j] * wo[j];
#pragma unroll
        for (int o2 = 1; o2 < 64; o2 <<= 1) sd += __shfl_xor(sd, o2, 64);
        if (tid == 0) {
          int tt = k - 1;
          float val = 0.f;
          if (tt < sm->sLmax[s & 1])
            val = (tt > sm->sLens[s & 1][b_o]) ? bo_r : (sd + bo_r);
          out[(((4 * team + b_o) * 24 + s) * 48 + tt) * 5 + o_o] = val;
        }
      }
    }
  }
}

extern "C" void kernel_launch(void* const* d_in, const int* in_sizes, int n_in,
                              void* d_out, int out_size, void* d_ws, size_t ws_size,
                              hipStream_t stream) {
  (void)in_sizes; (void)n_in; (void)out_size; (void)ws_size;
  // Pad LDS to 96KB: forces 1 block/CU so the persistent grid maps 1:1 to CUs.
  int lds_bytes = 98304;
  hipFuncSetAttribute((const void*)rnn_decoder_kernel,
                      hipFuncAttributeMaxDynamicSharedMemorySize, lds_bytes);
  // zero all team exchange regions (seq 0 != any expected seq >= 1)
  hipMemsetAsync(d_ws, 0, 8 * 6144 * 8, stream);
  rnn_decoder_kernel<<<dim3(NB), dim3(NT), lds_bytes, stream>>>(
      (const float*)d_in[0],   // enc_features
      (const float*)d_in[1],   // vector_sketch
      (const int*)d_in[3],     // batch_stroke_len
      (const float*)d_in[4],   // W_sc_ih
      (const float*)d_in[5],   // W_sc_hh
      (const float*)d_in[6],   // b_sc
      (const float*)d_in[7],   // W0_ih
      (const float*)d_in[8],   // W0_hh
      (const float*)d_in[9],   // b0
      (const float*)d_in[10],  // W1_ih
      (const float*)d_in[11],  // W1_hh
      (const float*)d_in[12],  // b1
      (const float*)d_in[13],  // W_out
      (const float*)d_in[14],  // b_out
      (float*)d_out, (float*)d_ws);
}